// Round 11
// baseline (45.744 us; speedup 1.0000x reference)
//
#include <hip/hip_runtime.h>
#include <math.h>

// x: (32,32,32,32) f32; 6 layers, O=64 trees, gates/layer = 32,16,8,4,2,1
// out: (32,64,32,32) f32
//
// Fused-expansion formulation: root gate's dependency cone expanded as a
// binary tree = 63 nodes. Precomputed coefs -> evaluation has ONLY static
// indices. Leaf operand A comes from an LDS slab (ds pipe); leaf operand B
// from a padded global copy of x (VMEM pipe, L2/L3-resident) -> the two
// memory pipes run in parallel, halving the former ds bottleneck.
//
// d_ws layout (dwords), per tree o (320 dwords):
//   tab[o*320 +   0..31]  packed LDS leaf offsets (offa | offb<<16)  [stride-35 slab]
//   tab[o*320 +  32..283] float4 coefs: L0 n->n, L1->32+n, L2->48+n, L3->56+n,
//                         L4->60+n, L5->62
//   tab[o*320 + 288..319] goffB: dword offset of operand B in padded xp
// xp (at dword 20480): [b][ch][r=0..33][72]; dword i in row: i<36 -> copyA
//   col=i-1; i>=36 -> copyB col=i-38. Parity chosen so (inrow + even j) is
//   always even -> aligned float2. Size 2,506,752 dwords (10.0 MB).

struct Tabs { const int* ia[6]; const int* ib[6]; const float* w[6]; };

#define TAB_STRIDE 320
#define XP_OFF_DW  20480
#define XP_DWORDS  2506752

__device__ __constant__ float GM[64] = {
  0,0,0,0,   0,0,0,1,   0,1,0,-1,  0,1,0,0,
  0,0,1,-1,  0,0,1,0,   0,1,1,-2,  0,1,1,-1,
  1,-1,-1,1, 1,-1,-1,2, 1,0,-1,0,  1,0,-1,1,
  1,-1,0,0,  1,-1,0,1,  1,0,0,-1,  1,0,0,0 };

typedef float v2f __attribute__((ext_vector_type(2)));

// packed gate: y = c0 + c1*a + c2*b + c3*a*b  -> 3x v_pk_fma_f32
__device__ __forceinline__ v2f gatep(v2f a, v2f b, float4 c) {
  v2f t = __builtin_elementwise_fma((v2f)c.w, b, (v2f)c.y);
  t = __builtin_elementwise_fma(a, t, (v2f)c.x);
  return __builtin_elementwise_fma((v2f)c.z, b, t);
}

// ---- builder: one thread per expanded node ----
__global__ __launch_bounds__(256) void build_tree(Tabs t, unsigned* __restrict tab) {
  const int gid = blockIdx.x * 256 + threadIdx.x;     // [0, 4096)
  const int o = gid >> 6, slot = gid & 63;
  if (slot >= 63) return;
  int L, m;
  if      (slot < 32) { L = 0; m = slot;      }
  else if (slot < 48) { L = 1; m = slot - 32; }
  else if (slot < 56) { L = 2; m = slot - 48; }
  else if (slot < 60) { L = 3; m = slot - 56; }
  else if (slot < 62) { L = 4; m = slot - 60; }
  else                { L = 5; m = 0;         }
  const int dcnt[6] = {32, 16, 8, 4, 2, 1};
  const int d = 5 - L;
  int g = 0;
  for (int step = 0; step < d; ++step) {
    int lyr = 5 - step;
    int bit = (m >> (d - 1 - step)) & 1;
    g = (bit ? t.ib[lyr] : t.ia[lyr])[o * dcnt[lyr] + g];
  }

  const float4* wp = (const float4*)(t.w[L] + (o * dcnt[L] + g) * 16);
  float4 w0 = wp[0], w1 = wp[1], w2 = wp[2], w3 = wp[3];
  float wv[16] = { w0.x,w0.y,w0.z,w0.w, w1.x,w1.y,w1.z,w1.w,
                   w2.x,w2.y,w2.z,w2.w, w3.x,w3.y,w3.z,w3.w };
  float mx = -1e30f;
  #pragma unroll
  for (int k = 0; k < 16; ++k) mx = fmaxf(mx, wv[k]);
  float e[16], s = 0.f;
  #pragma unroll
  for (int k = 0; k < 16; ++k) { e[k] = expf(wv[k] - mx); s += e[k]; }
  float inv = 1.0f / s;
  float c0 = 0, c1 = 0, c2 = 0, c3 = 0;
  #pragma unroll
  for (int k = 0; k < 16; ++k) {
    float p = e[k] * inv;
    c0 += p * GM[k*4+0]; c1 += p * GM[k*4+1];
    c2 += p * GM[k*4+2]; c3 += p * GM[k*4+3];
  }
  float4* C = (float4*)(tab + o * TAB_STRIDE + 32);
  float4 c; c.x = c0; c.y = c1; c.z = c2; c.w = c3;
  C[slot] = c;

  if (L == 0) {
    int ia = t.ia[0][o * 32 + g], ib = t.ib[0][o * 32 + g];
    int ca = ia / 9, ra = ia - ca * 9, kia = ra / 3, kja = ra - kia * 3;
    int cb = ib / 9, rb = ib - cb * 9, kib = rb / 3, kjb = rb - kib * 3;
    // LDS offsets (stride-35 slab), for both the fallback and operand A
    unsigned offa = (unsigned)((ca * 6 + kia) * 35 + kja);
    unsigned offb = (unsigned)((cb * 6 + kib) * 35 + kjb);
    tab[o * TAB_STRIDE + slot] = offa | (offb << 16);
    // global padded-copy offset for operand B: row = kib (+r0+rbase at run),
    // in-row base: parity of (kjb-1): odd -> copyA idx kjb; even -> copyB 38
    unsigned inrow = (kjb == 1) ? 38u : (unsigned)kjb;
    tab[o * TAB_STRIDE + 288 + slot] = (unsigned)(cb * 2448 + kib * 72) + inrow;
  }
}

// ---- prep: padded dual-parity global copy of x ----
__global__ __launch_bounds__(256) void prep(const float* __restrict x,
                                            float* __restrict xp) {
  int idx = blockIdx.x * 256 + threadIdx.x;
  if (idx >= XP_DWORDS) return;
  int i = idx % 72;
  int rowid = idx / 72;
  int r = rowid % 34;            // padded row; real row = r-1
  int bc = rowid / 34;           // b*32 + ch
  int col = (i < 36) ? (i - 1) : (i - 38);
  int gr = r - 1;
  float v = 0.f;
  if ((unsigned)gr < 32u && (unsigned)col < 32u)
    v = x[(bc * 32 + gr) * 32 + col];
  xp[idx] = v;
}

// ---- main kernel, split-pipe variant ----
// Block: 512 threads = 8 waves sharing one 4-row x 32-col tile; each lane owns
// 2 adjacent cols; wave does 2 trees. 32 waves/CU resident. LDS 26.25 KiB.
__global__ __launch_bounds__(512, 8) void logic_conv_g(const float* __restrict x,
                                                       const unsigned* __restrict tab,
                                                       const float* __restrict xp,
                                                       float* __restrict out) {
  __shared__ float xr[6720];                     // 32ch * 6rows * 35
  const int bid = blockIdx.x;
  const int tc = bid & 3, rc = (bid >> 2) & 7, b = bid >> 5;
  const int r0 = rc * 4;
  const int tid = threadIdx.x;

  for (int idx = tid; idx < 6720; idx += 512) {
    int c = idx / 210, rem = idx - c * 210;
    int rr = rem / 35, sc = rem - rr * 35;
    int gr = r0 - 1 + rr, gc = sc - 1;
    float v = 0.f;
    if ((unsigned)gr < 32u && (unsigned)gc < 32u)
      v = x[((b * 32 + c) * 32 + gr) * 32 + gc];
    xr[idx] = v;
  }
  __syncthreads();

  const int w = tid >> 6;
  const int lane = tid & 63;
  const int rbase = lane >> 4;
  const int j = (lane & 15) * 2;
  const int lbase = rbase * 35 + j;
  const int o0 = tc * 16 + w * 2;
  // per-lane dword base into xp: b*(32*34*72) + (r0+rbase)*72 + j
  const int blg = b * 78336 + (r0 + rbase) * 72 + j;
  const float* __restrict xpl = xp + blg;
  float* outb = out + ((b * 64 + o0) * 32 + (r0 + rbase)) * 32 + j;

  for (int t = 0; t < 2; ++t) {
    const int o = __builtin_amdgcn_readfirstlane(o0 + t);
    const unsigned* __restrict T  = tab + o * TAB_STRIDE;
    const float4*  __restrict C  = (const float4*)(T + 32);
    const unsigned* __restrict G2 = T + 288;

    v2f t1[16];
    #pragma unroll
    for (int n = 0; n < 16; ++n) {
      unsigned ipA = T[2*n], ipB = T[2*n+1];
      // gate 2n: A from LDS, B from padded global (VMEM pipe)
      int oa = (int)(ipA & 0xffffu) + lbase;
      v2f a; a.x = xr[oa]; a.y = xr[oa + 1];     // ds_read2_b32
      float2 fb = *(const float2*)(xpl + (int)G2[2*n]);
      v2f bb = {fb.x, fb.y};
      v2f u = gatep(a, bb, C[2*n]);
      // gate 2n+1
      int oc = (int)(ipB & 0xffffu) + lbase;
      v2f cc; cc.x = xr[oc]; cc.y = xr[oc + 1];
      float2 fd = *(const float2*)(xpl + (int)G2[2*n+1]);
      v2f dd = {fd.x, fd.y};
      v2f v = gatep(cc, dd, C[2*n+1]);
      t1[n] = gatep(u, v, C[32 + n]);
    }
    v2f t2[8];
    #pragma unroll
    for (int n = 0; n < 8; ++n) t2[n] = gatep(t1[2*n], t1[2*n+1], C[48 + n]);
    v2f t3[4];
    #pragma unroll
    for (int n = 0; n < 4; ++n) t3[n] = gatep(t2[2*n], t2[2*n+1], C[56 + n]);
    v2f t4[2];
    #pragma unroll
    for (int n = 0; n < 2; ++n) t4[n] = gatep(t3[2*n], t3[2*n+1], C[60 + n]);
    {
      v2f r = gatep(t4[0], t4[1], C[62]);
      float2 rr; rr.x = r.x; rr.y = r.y;
      *(float2*)outb = rr;
    }
    outb += 1024;
  }
}

// ---- fallback: exact R8 all-LDS kernel (used if ws too small for xp) ----
__global__ __launch_bounds__(512, 8) void logic_conv_r(const float* __restrict x,
                                                       const unsigned* __restrict tab,
                                                       float* __restrict out) {
  __shared__ float xr[6720];
  const int bid = blockIdx.x;
  const int tc = bid & 3, rc = (bid >> 2) & 7, b = bid >> 5;
  const int r0 = rc * 4;
  const int tid = threadIdx.x;

  for (int idx = tid; idx < 6720; idx += 512) {
    int c = idx / 210, rem = idx - c * 210;
    int rr = rem / 35, sc = rem - rr * 35;
    int gr = r0 - 1 + rr, gc = sc - 1;
    float v = 0.f;
    if ((unsigned)gr < 32u && (unsigned)gc < 32u)
      v = x[((b * 32 + c) * 32 + gr) * 32 + gc];
    xr[idx] = v;
  }
  __syncthreads();

  const int w = tid >> 6;
  const int lane = tid & 63;
  const int rbase = lane >> 4;
  const int j = (lane & 15) * 2;
  const int lbase = rbase * 35 + j;
  const int o0 = tc * 16 + w * 2;
  float* outb = out + ((b * 64 + o0) * 32 + (r0 + rbase)) * 32 + j;

  for (int t = 0; t < 2; ++t) {
    const int o = __builtin_amdgcn_readfirstlane(o0 + t);
    const unsigned* __restrict T = tab + o * TAB_STRIDE;
    const float4*  __restrict C = (const float4*)(T + 32);

    v2f t1[16];
    #pragma unroll
    for (int n = 0; n < 16; ++n) {
      unsigned ipA = T[2*n], ipB = T[2*n+1];
      int oa = (int)(ipA & 0xffffu) + lbase;
      int ob = (int)(ipA >> 16) + lbase;
      v2f a, bb;
      a.x = xr[oa]; a.y = xr[oa + 1];
      bb.x = xr[ob]; bb.y = xr[ob + 1];
      v2f u = gatep(a, bb, C[2*n]);
      oa = (int)(ipB & 0xffffu) + lbase;
      ob = (int)(ipB >> 16) + lbase;
      v2f cc, dd;
      cc.x = xr[oa]; cc.y = xr[oa + 1];
      dd.x = xr[ob]; dd.y = xr[ob + 1];
      v2f v = gatep(cc, dd, C[2*n+1]);
      t1[n] = gatep(u, v, C[32 + n]);
    }
    v2f t2[8];
    #pragma unroll
    for (int n = 0; n < 8; ++n) t2[n] = gatep(t1[2*n], t1[2*n+1], C[48 + n]);
    v2f t3[4];
    #pragma unroll
    for (int n = 0; n < 4; ++n) t3[n] = gatep(t2[2*n], t2[2*n+1], C[56 + n]);
    v2f t4[2];
    #pragma unroll
    for (int n = 0; n < 2; ++n) t4[n] = gatep(t3[2*n], t3[2*n+1], C[60 + n]);
    {
      v2f r = gatep(t4[0], t4[1], C[62]);
      float2 rr; rr.x = r.x; rr.y = r.y;
      *(float2*)outb = rr;
    }
    outb += 1024;
  }
}

extern "C" void kernel_launch(void* const* d_in, const int* in_sizes, int n_in,
                              void* d_out, int out_size, void* d_ws, size_t ws_size,
                              hipStream_t stream) {
  const float* x = (const float*)d_in[0];
  Tabs tabs;
  for (int l = 0; l < 6; ++l) {
    tabs.ia[l] = (const int*)d_in[1 + 3 * l];
    tabs.ib[l] = (const int*)d_in[2 + 3 * l];
    tabs.w[l]  = (const float*)d_in[3 + 3 * l];
  }
  unsigned* tab = (unsigned*)d_ws;               // 64*320 dw = 81920 B
  build_tree<<<16, 256, 0, stream>>>(tabs, tab);

  const size_t need = (size_t)(XP_OFF_DW + XP_DWORDS) * 4;   // ~10.1 MB
  if (ws_size >= need) {
    float* xp = (float*)d_ws + XP_OFF_DW;
    prep<<<(XP_DWORDS + 255) / 256, 256, 0, stream>>>(x, xp);
    logic_conv_g<<<1024, 512, 0, stream>>>(x, tab, xp, (float*)d_out);
  } else {
    logic_conv_r<<<1024, 512, 0, stream>>>(x, tab, (float*)d_out);
  }
}

// Round 12
// 28.783 us; speedup vs baseline: 1.5893x; 1.5893x over previous
//
#include <hip/hip_runtime.h>
#include <math.h>

// x: (32,32,32,32) f32; 6 layers, O=64 trees, gates/layer = 32,16,8,4,2,1
// out: (32,64,32,32) f32
//
// Fused-expansion formulation: the root gate's dependency cone expanded as a
// binary tree = 63 nodes (1+2+4+8+16+32). Precompute expanded coefs ->
// evaluation has ONLY static indices: t1[n] = gate(t0[2n], t0[2n+1]).
//
// d_ws layout (dwords), per tree o (288 dwords, 16B aligned):
//   tab[o*288 + 0..31]    packed leaf slab offsets (offa | offb<<16), L0 node n
//   tab[o*288 + 32..283]  float4 coefs, slots: L0 n->n, L1->32+n, L2->48+n,
//                         L3->56+n, L4->60+n, L5->62
// Slab geometry: xr[ch][6][35] (35-dword row stride), lane adds rbase*35 + j.

struct Tabs { const int* ia[6]; const int* ib[6]; const float* w[6]; };

__device__ __constant__ float GM[64] = {
  0,0,0,0,   0,0,0,1,   0,1,0,-1,  0,1,0,0,
  0,0,1,-1,  0,0,1,0,   0,1,1,-2,  0,1,1,-1,
  1,-1,-1,1, 1,-1,-1,2, 1,0,-1,0,  1,0,-1,1,
  1,-1,0,0,  1,-1,0,1,  1,0,0,-1,  1,0,0,0 };

typedef float v2f __attribute__((ext_vector_type(2)));

// packed gate: y = c0 + c1*a + c2*b + c3*a*b on both pixels at once
// = fma(c2,b, fma(a, fma(c3,b,c1), c0))  -> 3x v_pk_fma_f32
__device__ __forceinline__ v2f gatep(v2f a, v2f b, float4 c) {
  v2f t = __builtin_elementwise_fma((v2f)c.w, b, (v2f)c.y);
  t = __builtin_elementwise_fma(a, t, (v2f)c.x);
  return __builtin_elementwise_fma((v2f)c.z, b, t);
}

// ---- builder: one thread per expanded node; walks its own root->node path ----
__global__ __launch_bounds__(256) void build_tree(Tabs t, unsigned* __restrict tab) {
  const int gid = blockIdx.x * 256 + threadIdx.x;     // [0, 4096)
  const int o = gid >> 6, slot = gid & 63;
  if (slot >= 63) return;
  int L, m;
  if      (slot < 32) { L = 0; m = slot;      }
  else if (slot < 48) { L = 1; m = slot - 32; }
  else if (slot < 56) { L = 2; m = slot - 48; }
  else if (slot < 60) { L = 3; m = slot - 56; }
  else if (slot < 62) { L = 4; m = slot - 60; }
  else                { L = 5; m = 0;         }
  const int dcnt[6] = {32, 16, 8, 4, 2, 1};
  const int d = 5 - L;                 // path length from root
  int g = 0;                           // gate id at current level (root = gate 0)
  for (int step = 0; step < d; ++step) {
    int lyr = 5 - step;
    int bit = (m >> (d - 1 - step)) & 1;
    g = (bit ? t.ib[lyr] : t.ia[lyr])[o * dcnt[lyr] + g];
  }

  // coefficients: softmax(w[L][o, g]) @ GATE_M
  const float4* wp = (const float4*)(t.w[L] + (o * dcnt[L] + g) * 16);
  float4 w0 = wp[0], w1 = wp[1], w2 = wp[2], w3 = wp[3];
  float wv[16] = { w0.x,w0.y,w0.z,w0.w, w1.x,w1.y,w1.z,w1.w,
                   w2.x,w2.y,w2.z,w2.w, w3.x,w3.y,w3.z,w3.w };
  float mx = -1e30f;
  #pragma unroll
  for (int k = 0; k < 16; ++k) mx = fmaxf(mx, wv[k]);
  float e[16], s = 0.f;
  #pragma unroll
  for (int k = 0; k < 16; ++k) { e[k] = expf(wv[k] - mx); s += e[k]; }
  float inv = 1.0f / s;
  float c0 = 0, c1 = 0, c2 = 0, c3 = 0;
  #pragma unroll
  for (int k = 0; k < 16; ++k) {
    float p = e[k] * inv;
    c0 += p * GM[k*4+0]; c1 += p * GM[k*4+1];
    c2 += p * GM[k*4+2]; c3 += p * GM[k*4+3];
  }
  float4* C = (float4*)(tab + o * 288 + 32);
  float4 c; c.x = c0; c.y = c1; c.z = c2; c.w = c3;
  C[slot] = c;

  if (L == 0) {
    // leaf slab offsets: feature f = ch*9 + ki*3 + kj -> xr[ch][6][35] offset
    int ia = t.ia[0][o * 32 + g], ib = t.ib[0][o * 32 + g];
    int ca = ia / 9, ra = ia - ca * 9, kia = ra / 3, kja = ra - kia * 3;
    int cb = ib / 9, rb = ib - cb * 9, kib = rb / 3, kjb = rb - kib * 3;
    unsigned offa = (unsigned)((ca * 6 + kia) * 35 + kja);
    unsigned offb = (unsigned)((cb * 6 + kib) * 35 + kjb);
    tab[o * 288 + slot] = offa | (offb << 16);
  }
}

// Block: 512 threads = 8 waves, all sharing one 4-row x 32-col tile.
// Each lane owns 2 adjacent columns (ds_read2_b32 leaf reads, dwordx2 stores,
// pk_fma 2x-packed gate math). Each wave evaluates 2 trees -> 8192 waves
// total = 32 waves/CU resident (grid 1024 = 4 blocks/CU x 8 waves).
// LDS slab 32ch x 6rows x 35 = 26.25 KiB; 4 blocks/CU = 105 KiB.
// bid bits: [1:0]=treechunk(16 trees), [4:2]=rowchunk(4 rows), [9:5]=batch
__global__ __launch_bounds__(512, 8) void logic_conv(const float* __restrict x,
                                                     const unsigned* __restrict tab,
                                                     float* __restrict out) {
  __shared__ float xr[6720];                     // 32ch * 6rows * 35
  const int bid = blockIdx.x;
  const int tc = bid & 3, rc = (bid >> 2) & 7, b = bid >> 5;
  const int r0 = rc * 4;
  const int tid = threadIdx.x;

  // stage input slab: rows r0-1 .. r0+4, cols -1..32 (+1 pad), zero OOB
  for (int idx = tid; idx < 6720; idx += 512) {
    int c = idx / 210, rem = idx - c * 210;
    int rr = rem / 35, sc = rem - rr * 35;
    int gr = r0 - 1 + rr, gc = sc - 1;
    float v = 0.f;
    if ((unsigned)gr < 32u && (unsigned)gc < 32u)
      v = x[((b * 32 + c) * 32 + gr) * 32 + gc];
    xr[idx] = v;
  }
  __syncthreads();

  const int w = tid >> 6;              // wave id 0..7 -> tree pair
  const int lane = tid & 63;
  const int rbase = lane >> 4;         // 0..3 relative output row
  const int j = (lane & 15) * 2;       // 0,2,..,30 (col pair)
  const int lbase = rbase * 35 + j;
  const int o0 = tc * 16 + w * 2;      // first tree for this wave
  float* outb = out + ((b * 64 + o0) * 32 + (r0 + rbase)) * 32 + j;

  for (int t = 0; t < 2; ++t) {
    const int o = __builtin_amdgcn_readfirstlane(o0 + t);   // uniform -> s_load
    const unsigned* __restrict T = tab + o * 288;
    const float4*  __restrict C = (const float4*)(T + 32);

    // fused L0+L1: consume leaf pairs immediately (caps VGPR pressure)
    v2f t1[16];
    #pragma unroll
    for (int n = 0; n < 16; ++n) {
      unsigned ipA = T[2*n], ipB = T[2*n+1];
      int oa = (int)(ipA & 0xffffu) + lbase;
      int ob = (int)(ipA >> 16) + lbase;
      v2f a, bb;
      a.x = xr[oa]; a.y = xr[oa + 1];            // -> ds_read2_b32
      bb.x = xr[ob]; bb.y = xr[ob + 1];
      v2f u = gatep(a, bb, C[2*n]);
      oa = (int)(ipB & 0xffffu) + lbase;
      ob = (int)(ipB >> 16) + lbase;
      v2f cc, dd;
      cc.x = xr[oa]; cc.y = xr[oa + 1];
      dd.x = xr[ob]; dd.y = xr[ob + 1];
      v2f v = gatep(cc, dd, C[2*n+1]);
      t1[n] = gatep(u, v, C[32 + n]);
    }
    v2f t2[8];
    #pragma unroll
    for (int n = 0; n < 8; ++n) t2[n] = gatep(t1[2*n], t1[2*n+1], C[48 + n]);
    v2f t3[4];
    #pragma unroll
    for (int n = 0; n < 4; ++n) t3[n] = gatep(t2[2*n], t2[2*n+1], C[56 + n]);
    v2f t4[2];
    #pragma unroll
    for (int n = 0; n < 2; ++n) t4[n] = gatep(t3[2*n], t3[2*n+1], C[60 + n]);
    {
      v2f r = gatep(t4[0], t4[1], C[62]);
      float2 rr; rr.x = r.x; rr.y = r.y;
      *(float2*)outb = rr;                       // 8B aligned (j even)
    }
    outb += 1024;                      // next tree: +32*32
  }
}

extern "C" void kernel_launch(void* const* d_in, const int* in_sizes, int n_in,
                              void* d_out, int out_size, void* d_ws, size_t ws_size,
                              hipStream_t stream) {
  const float* x = (const float*)d_in[0];
  Tabs tabs;
  for (int l = 0; l < 6; ++l) {
    tabs.ia[l] = (const int*)d_in[1 + 3 * l];
    tabs.ib[l] = (const int*)d_in[2 + 3 * l];
    tabs.w[l]  = (const float*)d_in[3 + 3 * l];
  }
  unsigned* tab = (unsigned*)d_ws;     // 64 trees * 288 dwords = 73.7 KB
  build_tree<<<16, 256, 0, stream>>>(tabs, tab);
  logic_conv<<<1024, 512, 0, stream>>>(x, tab, (float*)d_out);
}